// Round 17
// baseline (59.489 us; speedup 1.0000x reference)
//
#include <hip/hip_runtime.h>
#include <hip/hip_bf16.h>

typedef __attribute__((ext_vector_type(8))) short short8;   // 8 x bf16 (4 VGPR)
typedef __attribute__((ext_vector_type(4))) float f32x4;
typedef __attribute__((ext_vector_type(4))) int   i32x4;

#define KD 4096
#define ND 16384
#define MD 128

// round-to-nearest-even f32 -> bf16 bits
__device__ __forceinline__ ushort f2bf_rn(float f) {
    unsigned u = __float_as_uint(f);
    u += 0x7FFFu + ((u >> 16) & 1u);
    return (ushort)(u >> 16);
}

// exact for |v| <= 127: int -> f32 -> truncate to bf16 (small ints have zero low mantissa bits)
__device__ __forceinline__ ushort i2bf(int v) {
    return (ushort)(__float_as_uint((float)v) >> 16);
}

// Pack x[128][4096] f32 into bf16 MFMA A-fragment order (verified r1/r3):
// xp[kb][mt][lane][j] = x[16*mt + (lane&15)][32*kb + 8*(lane>>4) + j]   (1 MiB)
__global__ __launch_bounds__(256) void pack_x_kernel(const float* __restrict__ x,
                                                     ushort* __restrict__ xp) {
    int tid  = blockIdx.x * 256 + threadIdx.x;   // 0..65535
    int lane = tid & 63;
    int mt   = (tid >> 6) & 7;
    int kb   = tid >> 9;                          // 0..127
    int m = (mt << 4) + (lane & 15);
    int k = (kb << 5) + ((lane >> 4) << 3);
    const f32x4* src = reinterpret_cast<const f32x4*>(x + (size_t)m * KD + k);
    f32x4 a = src[0];
    f32x4 b = src[1];
    short8 v;
    v[0] = (short)f2bf_rn(a[0]); v[1] = (short)f2bf_rn(a[1]);
    v[2] = (short)f2bf_rn(a[2]); v[3] = (short)f2bf_rn(a[3]);
    v[4] = (short)f2bf_rn(b[0]); v[5] = (short)f2bf_rn(b[1]);
    v[6] = (short)f2bf_rn(b[2]); v[7] = (short)f2bf_rn(b[3]);
    *reinterpret_cast<short8*>(xp + (size_t)tid * 8) = v;
}

#define GLOAD_LDS16(g, l)                                                        \
    __builtin_amdgcn_global_load_lds((const __attribute__((address_space(1))) void*)(g), \
                                     (__attribute__((address_space(3))) void*)(l), 16, 0, 0)

// Producer/consumer wave specialization (verified r10) with W staged in K=128 PAIRS:
// each W gload_lds now reads 512B contiguous per column (2 cols x 512B = 1024B per
// instruction) instead of 256B -> 2x bytes per DRAM row activation. A unchanged
// (per-phase 16 KiB chunks from L2-resident xp).
// Block = 512 threads (8 waves), grid 256 (1 block/CU). Tile: 64 cols x 128 rows x full K.
//   waves 0..3  CONSUMERS: 16 cols each, acc[8]; plain __syncthreads() (vmcnt empty).
//   waves 4..7  PRODUCERS: even phase t: issue A(t+2)[4] + Wpair(t/2+1)[8], vmcnt(12)
//               (retires A(t+1)); odd phase t: issue A(t+2)[4], vmcnt(4) (retires
//               A(t+1..t+2)-1 and the W pair). In-order-retire audit in comments.
// LDS: A 3x16K [0,48K) chunk%3 + W 2x32K [48K,112K) pair%2 = 112 KiB.
__global__ __launch_bounds__(512) void gemm_kernel(const int* __restrict__ wgt,
                                                   const ushort* __restrict__ xp,
                                                   const float* __restrict__ scales,
                                                   const float* __restrict__ bias,
                                                   float* __restrict__ out) {
    __shared__ __align__(16) char lds[114688];   // 48K A + 64K W

    const int tid  = threadIdx.x;
    const int lane = tid & 63;
    const int w    = tid >> 6;          // wave 0..7
    const int n0   = blockIdx.x << 6;   // 256 blocks x 64 cols
    const int cl   = lane & 15;
    const int cq   = lane >> 4;         // 0..3

    if (w >= 4) {
        // ================= PRODUCER =================
        const int p = w - 4;            // 0..3
        // A: r10 verbatim — chunk c: 4 issues from asrc + c*16384
        const char* asrc = (const char*)xp + (p << 12) + (lane << 4);
        // W pair sources: issue i covers cols c = 16p + 2i + (lane>>5);
        // lane l stores k-index ((l&31) ^ (c&7))*4 of the pair's 128-k window
        // -> realizes read layout byte(c,k) = (4k) ^ ((c&7)<<4) in [0,512) per col.
        const int* wsrc[8];
#pragma unroll
        for (int i = 0; i < 8; ++i) {
            int c = (p << 4) + (i << 1) + (lane >> 5);
            int koff = (((lane & 31) ^ (c & 7)) << 2);
            wsrc[i] = wgt + (size_t)(n0 + c) * KD + koff;
        }
        char* dA = lds + (p << 12);              // + bufA*16384 + j*1024
        char* dW = lds + 49152 + (p << 13);      // + bufW*32768 + i*1024

#define STAGE_A(c, b) do {                                                      \
            const char* _as = asrc + (size_t)(c) * 16384;                       \
            char* _dA = dA + (b) * 16384;                                       \
            GLOAD_LDS16(_as,        _dA);                                       \
            GLOAD_LDS16(_as + 1024, _dA + 1024);                                \
            GLOAD_LDS16(_as + 2048, _dA + 2048);                                \
            GLOAD_LDS16(_as + 3072, _dA + 3072);                                \
        } while (0)

#define STAGE_W(u, b) do {                                                      \
            const int _k0 = (u) * 128;                                          \
            char* _dW = dW + (b) * 32768;                                       \
            _Pragma("unroll")                                                   \
            for (int _i = 0; _i < 8; ++_i)                                      \
                GLOAD_LDS16(wsrc[_i] + _k0, _dW + _i * 1024);                   \
        } while (0)

        // ---- prologue: A0, Wp0, A1 issued; wait leaves A1 in flight ----
        STAGE_A(0, 0);
        STAGE_W(0, 0);
        STAGE_A(1, 1);
        asm volatile("s_waitcnt vmcnt(4)" ::: "memory");   // A0 + Wp0 landed
        __builtin_amdgcn_s_barrier();                       // entry barrier

        int ba = 2;                     // buffer of A chunk t+2 (= (t+2)%3)
#pragma unroll 1
        for (int t = 0; t < 64; ++t) {
            if (t < 62) {
                STAGE_A(t + 2, ba);
                if ((t & 1) == 0) STAGE_W((t >> 1) + 1, ((t >> 1) + 1) & 1);
            }
            // in-order retire audit:
            //  even t<62: outstanding A(t+1)4 + A(t+2)4 + Wp8 = 16 -> vmcnt(12)
            //             retires A(t+1); phase t+1 needs A(t+1) + landed W half.
            //  odd  t<62: outstanding A(t+1)4? no: A(t+1) retired at t-1; here
            //             A(t+2)prev4? -> [A(t+1)=none] A(t+... ) = A(t+1)?  --
            //             outstanding = A(t+1-1+2)=A(t+1)? none. Actual: A(t+2)4
            //             issued now + A(t+1)4? retired at even t-1 -> pre-issue
            //             outstanding = A(t+1? ) ... = Wp(u+1)8 + A(t+1)4? no:
            //             = A(t+1)(retired) -> [A(t+2-1)=A(t+1)] gone; remaining
            //             = A((t-1)+2)=A(t+1)? retired. So pre = Wp8 + A? = 12;
            //             post-issue 16 -> vmcnt(4) retires A(t+1-?)... leaves
            //             only the newest A: guarantees A(t+1)+Wpair landed.
            //  t>=62: drain everything -> vmcnt(0).
            if (t >= 62) {
                asm volatile("s_waitcnt vmcnt(0)" ::: "memory");
            } else if (t & 1) {
                asm volatile("s_waitcnt vmcnt(4)" ::: "memory");
            } else {
                asm volatile("s_waitcnt vmcnt(12)" ::: "memory");
            }
            __builtin_amdgcn_s_barrier();
            ba = (ba == 2) ? 0 : ba + 1;
        }
#undef STAGE_A
#undef STAGE_W
        return;   // producers write no output
    }

    // ================= CONSUMER (waves 0..3) =================
    f32x4 acc[8];
#pragma unroll
    for (int i = 0; i < 8; ++i) acc[i] = (f32x4){0.f, 0.f, 0.f, 0.f};

    // A read base: r10 verbatim (buffer t%3)
    const char* rA = lds + (lane << 4);                     // + bufA*16384 + j*8192 + mt*1024
    // W read base: col (16w+cl) at 512 B stride within pair buffer
    const char* rW = lds + 49152 + (((w << 4) + cl) << 9);  // + bufW*32768 + swizzled off
    const unsigned sw  = (unsigned)((cl & 7) << 4);
    const unsigned q32 = (unsigned)(cq << 5);

    __syncthreads();                                        // entry barrier (vmcnt empty)

    int bc = 0;                                             // t % 3
#pragma unroll 1
    for (int t = 0; t < 64; ++t) {
        const char* wb = rW + (((t >> 1) & 1) << 15);       // pair buffer
        const unsigned hoff = (unsigned)((t & 1) << 8);     // chunk half within pair
        const char* ab = rA + bc * 16384;
#pragma unroll
        for (int j = 0; j < 2; ++j) {
            unsigned off = (hoff + (unsigned)((j << 7) + q32)) ^ sw;
            i32x4 lo = *reinterpret_cast<const i32x4*>(wb + off);
            i32x4 hi = *reinterpret_cast<const i32x4*>(wb + (off ^ 16u));
            short8 bf;
            bf[0] = (short)i2bf(lo[0]); bf[1] = (short)i2bf(lo[1]);
            bf[2] = (short)i2bf(lo[2]); bf[3] = (short)i2bf(lo[3]);
            bf[4] = (short)i2bf(hi[0]); bf[5] = (short)i2bf(hi[1]);
            bf[6] = (short)i2bf(hi[2]); bf[7] = (short)i2bf(hi[3]);
            const char* aj = ab + j * 8192;
#pragma unroll
            for (int mt = 0; mt < 8; ++mt) {
                short8 af = *reinterpret_cast<const short8*>(aj + mt * 1024);
                acc[mt] = __builtin_amdgcn_mfma_f32_16x16x32_bf16(af, bf, acc[mt], 0, 0, 0);
            }
        }
        __syncthreads();
        bc = (bc == 2) ? 0 : bc + 1;
    }

    // ---- epilogue: scale + bias, direct store (block owns 128 x 64 tile) ----
    const int ncol = n0 + (w << 4) + cl;
    const float s  = scales[ncol] * (1.0f / 127.0f);
    const float bv = bias[ncol];
    const int rb = cq << 2;
#pragma unroll
    for (int mt = 0; mt < 8; ++mt) {
#pragma unroll
        for (int r = 0; r < 4; ++r) {
            int mg = (mt << 4) + rb + r;
            out[(size_t)mg * ND + ncol] = acc[mt][r] * s + bv;
        }
    }
}

extern "C" void kernel_launch(void* const* d_in, const int* in_sizes, int n_in,
                              void* d_out, int out_size, void* d_ws, size_t ws_size,
                              hipStream_t stream) {
    const float* x      = (const float*)d_in[0];
    const int*   wgt    = (const int*)d_in[1];     // int8 promoted to int32 by harness
    const float* scales = (const float*)d_in[2];
    const float* bias   = (const float*)d_in[3];
    float* out = (float*)d_out;
    ushort* xp = (ushort*)d_ws;                    // 1 MiB bf16 packed x

    pack_x_kernel<<<MD * KD / (8 * 256), 256, 0, stream>>>(x, xp);
    gemm_kernel<<<256, 512, 0, stream>>>(wgt, xp, scales, bias, out);
}

// Round 18
// 58.142 us; speedup vs baseline: 1.0232x; 1.0232x over previous
//
#include <hip/hip_runtime.h>
#include <hip/hip_bf16.h>

typedef __attribute__((ext_vector_type(8))) short short8;   // 8 x bf16 (4 VGPR)
typedef __attribute__((ext_vector_type(4))) float f32x4;
typedef __attribute__((ext_vector_type(4))) int   i32x4;

#define KD 4096
#define ND 16384
#define MD 128

// round-to-nearest-even f32 -> bf16 bits
__device__ __forceinline__ ushort f2bf_rn(float f) {
    unsigned u = __float_as_uint(f);
    u += 0x7FFFu + ((u >> 16) & 1u);
    return (ushort)(u >> 16);
}

// exact for |v| <= 127: int -> f32 -> truncate to bf16 (small ints have zero low mantissa bits)
__device__ __forceinline__ ushort i2bf(int v) {
    return (ushort)(__float_as_uint((float)v) >> 16);
}

// Pack x[128][4096] f32 into bf16 MFMA A-fragment order (verified r1/r3):
// xp[kb][mt][lane][j] = x[16*mt + (lane&15)][32*kb + 8*(lane>>4) + j]   (1 MiB)
__global__ __launch_bounds__(256) void pack_x_kernel(const float* __restrict__ x,
                                                     ushort* __restrict__ xp) {
    int tid  = blockIdx.x * 256 + threadIdx.x;   // 0..65535
    int lane = tid & 63;
    int mt   = (tid >> 6) & 7;
    int kb   = tid >> 9;                          // 0..127
    int m = (mt << 4) + (lane & 15);
    int k = (kb << 5) + ((lane >> 4) << 3);
    const f32x4* src = reinterpret_cast<const f32x4*>(x + (size_t)m * KD + k);
    f32x4 a = src[0];
    f32x4 b = src[1];
    short8 v;
    v[0] = (short)f2bf_rn(a[0]); v[1] = (short)f2bf_rn(a[1]);
    v[2] = (short)f2bf_rn(a[2]); v[3] = (short)f2bf_rn(a[3]);
    v[4] = (short)f2bf_rn(b[0]); v[5] = (short)f2bf_rn(b[1]);
    v[6] = (short)f2bf_rn(b[2]); v[7] = (short)f2bf_rn(b[3]);
    *reinterpret_cast<short8*>(xp + (size_t)tid * 8) = v;
}

#define GLOAD_LDS16(g, l)                                                        \
    __builtin_amdgcn_global_load_lds((const __attribute__((address_space(1))) void*)(g), \
                                     (__attribute__((address_space(3))) void*)(l), 16, 0, 0)

// Producer/consumer wave specialization (verified r10 — best measured: 57.4 us).
// Block = 512 threads (8 waves), grid 256 (1 block/CU). Tile: 64 cols x 128 rows x full K.
// W fetched exactly once globally (intra-block reuse across all 8 m-tiles).
//   waves 0..3  CONSUMERS: compute 16 cols each, acc[8]; plain __syncthreads()
//               (their vmcnt queue is EMPTY -> the implicit vmcnt(0) is free, and
//               the legalizer inserts no vmcnt before their ds_reads).
//   waves 4..7  PRODUCERS: issue 8 global_load_lds per stage, 2 stages ahead,
//               raw s_barrier + counted vmcnt(8) (no ds_reads in these waves ->
//               nothing for the legalizer to poison).
// LDS: A 3x16K [0,48K) + W 3x16K [48K,96K), stage s -> buffer s%3.
__global__ __launch_bounds__(512) void gemm_kernel(const int* __restrict__ wgt,
                                                   const ushort* __restrict__ xp,
                                                   const float* __restrict__ scales,
                                                   const float* __restrict__ bias,
                                                   float* __restrict__ out) {
    __shared__ __align__(16) char lds[98304];

    const int tid  = threadIdx.x;
    const int lane = tid & 63;
    const int w    = tid >> 6;          // wave 0..7
    const int n0   = blockIdx.x << 6;   // 256 blocks x 64 cols
    const int cl   = lane & 15;
    const int cq   = lane >> 4;         // 0..3

    if (w >= 4) {
        // ================= PRODUCER =================
        const int p = w - 4;            // 0..3
        // A: segments s = p*4+i (16 x 1 KiB = full 16 KiB chunk), linear copy
        const char* asrc = (const char*)xp + (p << 12) + (lane << 4);
        // W: cols c = 16p + 4i + cq, pre-swizzled source (verified r3 layout:
        // off(c,k) = c*256 + ((4k) ^ ((c&7)<<4)))
        const int* wsrc0;
        const int* wsrc1;
        const int* wsrc2;
        const int* wsrc3;
        {
            int c0 = (p << 4) + 0  + cq;
            int c1 = (p << 4) + 4  + cq;
            int c2 = (p << 4) + 8  + cq;
            int c3 = (p << 4) + 12 + cq;
            wsrc0 = wgt + (size_t)(n0 + c0) * KD + ((cl ^ (c0 & 7)) << 2);
            wsrc1 = wgt + (size_t)(n0 + c1) * KD + ((cl ^ (c1 & 7)) << 2);
            wsrc2 = wgt + (size_t)(n0 + c2) * KD + ((cl ^ (c2 & 7)) << 2);
            wsrc3 = wgt + (size_t)(n0 + c3) * KD + ((cl ^ (c3 & 7)) << 2);
        }
        char* dA = lds + (p << 12);             // + b*16384 + i*1024
        char* dW = lds + 49152 + (p << 12);     // + b*16384 + i*1024

#define STAGE(t, b) do {                                                        \
            const char* _as = asrc + (size_t)(t) * 16384;                       \
            char* _dA = dA + (b) * 16384;                                       \
            GLOAD_LDS16(_as,        _dA);                                       \
            GLOAD_LDS16(_as + 1024, _dA + 1024);                                \
            GLOAD_LDS16(_as + 2048, _dA + 2048);                                \
            GLOAD_LDS16(_as + 3072, _dA + 3072);                                \
            const int _k0 = (t) * 64;                                           \
            char* _dW = dW + (b) * 16384;                                       \
            GLOAD_LDS16(wsrc0 + _k0, _dW);                                      \
            GLOAD_LDS16(wsrc1 + _k0, _dW + 1024);                               \
            GLOAD_LDS16(wsrc2 + _k0, _dW + 2048);                               \
            GLOAD_LDS16(wsrc3 + _k0, _dW + 3072);                               \
        } while (0)

        STAGE(0, 0);
        STAGE(1, 1);
        asm volatile("s_waitcnt vmcnt(8)" ::: "memory");   // stage 0 landed
        __builtin_amdgcn_s_barrier();                       // entry barrier

        int b2 = 2;                      // buffer of stage t+2
#pragma unroll 1
        for (int t = 0; t < 64; ++t) {
            if (t + 2 < 64) {
                STAGE(t + 2, b2);
                asm volatile("s_waitcnt vmcnt(8)" ::: "memory");  // stage t+1 landed
            } else if (t + 1 < 64) {
                asm volatile("s_waitcnt vmcnt(0)" ::: "memory");  // stage 63 landed
            }
            __builtin_amdgcn_s_barrier();
            b2 = (b2 == 2) ? 0 : b2 + 1;
        }
#undef STAGE
        return;   // producers write no output
    }

    // ================= CONSUMER (waves 0..3) =================
    f32x4 acc[8];
#pragma unroll
    for (int i = 0; i < 8; ++i) acc[i] = (f32x4){0.f, 0.f, 0.f, 0.f};

    // read bases (r3's verified patterns)
    const char* rA = lds + (lane << 4);                     // + b*16384 + j*8192 + mt*1024
    const char* rW = lds + 49152 + (((w << 4) + cl) << 8);  // + b*16384 + inner
    const unsigned sw  = (unsigned)((cl & 7) << 4);
    const unsigned q32 = (unsigned)(cq << 5);

    __syncthreads();                                        // entry barrier (vmcnt empty)

    int bc = 0;
#pragma unroll 1
    for (int t = 0; t < 64; ++t) {
        const char* wb = rW + bc * 16384;
        const char* ab = rA + bc * 16384;
#pragma unroll
        for (int j = 0; j < 2; ++j) {
            unsigned off = (unsigned)((j << 7) + q32) ^ sw;
            i32x4 lo = *reinterpret_cast<const i32x4*>(wb + off);
            i32x4 hi = *reinterpret_cast<const i32x4*>(wb + (off ^ 16u));
            short8 bf;
            bf[0] = (short)i2bf(lo[0]); bf[1] = (short)i2bf(lo[1]);
            bf[2] = (short)i2bf(lo[2]); bf[3] = (short)i2bf(lo[3]);
            bf[4] = (short)i2bf(hi[0]); bf[5] = (short)i2bf(hi[1]);
            bf[6] = (short)i2bf(hi[2]); bf[7] = (short)i2bf(hi[3]);
            const char* aj = ab + j * 8192;
#pragma unroll
            for (int mt = 0; mt < 8; ++mt) {
                short8 af = *reinterpret_cast<const short8*>(aj + mt * 1024);
                acc[mt] = __builtin_amdgcn_mfma_f32_16x16x32_bf16(af, bf, acc[mt], 0, 0, 0);
            }
        }
        __syncthreads();
        bc = (bc == 2) ? 0 : bc + 1;
    }

    // ---- epilogue: scale + bias, direct store (block owns 128 x 64 tile) ----
    const int ncol = n0 + (w << 4) + cl;
    const float s  = scales[ncol] * (1.0f / 127.0f);
    const float bv = bias[ncol];
    const int rb = cq << 2;
#pragma unroll
    for (int mt = 0; mt < 8; ++mt) {
#pragma unroll
        for (int r = 0; r < 4; ++r) {
            int mg = (mt << 4) + rb + r;
            out[(size_t)mg * ND + ncol] = acc[mt][r] * s + bv;
        }
    }
}

extern "C" void kernel_launch(void* const* d_in, const int* in_sizes, int n_in,
                              void* d_out, int out_size, void* d_ws, size_t ws_size,
                              hipStream_t stream) {
    const float* x      = (const float*)d_in[0];
    const int*   wgt    = (const int*)d_in[1];     // int8 promoted to int32 by harness
    const float* scales = (const float*)d_in[2];
    const float* bias   = (const float*)d_in[3];
    float* out = (float*)d_out;
    ushort* xp = (ushort*)d_ws;                    // 1 MiB bf16 packed x

    pack_x_kernel<<<MD * KD / (8 * 256), 256, 0, stream>>>(x, xp);
    gemm_kernel<<<256, 512, 0, stream>>>(wgt, xp, scales, bias, out);
}